// Round 3
// baseline (2889.810 us; speedup 1.0000x reference)
//
#include <hip/hip_runtime.h>
#include <hip/hip_bf16.h>
#include <stdint.h>

#define N_CELLS  512
#define N_PIX    25600
#define NBF      100      // n_bins_filter
#define MAXC     20
#define N_FRAMES 300
#define NBT      1500     // n_bins_total
#define N_INIT   100
#define T_STEPS  (NBT - N_INIT)   // 1400

#define RING   104        // logical ring (time mod RING)
#define RSTR   105        // LDS storage stride (odd -> conflict-free column writes)
#define NWG    64
#define CPW    (N_CELLS / NWG)    // 8 cells per WG
#define SCAN_THREADS (CPW * 64)   // 512
#define XDEPTH 8                  // exchange ring depth (skew bound ~3, min distance 5)

// ---------------- GEMM tiling ----------------
#define GT 64
#define GC 64
#define GK 64
#define KSPLIT 8
#define KCH (N_PIX / KSPLIT)      // 3200

// ============== GEMM partial: part[kb][t][c] = sum_{k in chunk} A[t,k]*B[c,k] ==============
__global__ __launch_bounds__(256) void gemm_partial_k(
        const float* __restrict__ A,   // input_frames [300][25600]
        const float* __restrict__ B,   // spat_filters [512][25600]
        float* __restrict__ part)      // [KSPLIT][300][512]
{
    __shared__ float As[GK][GT + 4];   // transposed: [k][row]
    __shared__ float Bs[GK][GC + 4];
    const int kb = blockIdx.x, tb = blockIdx.y, cb = blockIdx.z;
    const int tid = threadIdx.x;
    const int tx = tid & 15, ty = tid >> 4;
    const int t0 = tb * GT, c0 = cb * GC, k0 = kb * KCH;

    float acc[4][4];
    #pragma unroll
    for (int i = 0; i < 4; ++i)
        #pragma unroll
        for (int j = 0; j < 4; ++j) acc[i][j] = 0.f;

    for (int kc = 0; kc < KCH; kc += GK) {
        #pragma unroll
        for (int p = 0; p < 4; ++p) {
            const int r  = (tid >> 4) + p * 16;
            const int kk = (tid & 15) * 4;
            float4 av = make_float4(0.f, 0.f, 0.f, 0.f);
            if (t0 + r < N_FRAMES)
                av = *(const float4*)&A[(size_t)(t0 + r) * N_PIX + k0 + kc + kk];
            As[kk + 0][r] = av.x; As[kk + 1][r] = av.y;
            As[kk + 2][r] = av.z; As[kk + 3][r] = av.w;
            const float4 bv = *(const float4*)&B[(size_t)(c0 + r) * N_PIX + k0 + kc + kk];
            Bs[kk + 0][r] = bv.x; Bs[kk + 1][r] = bv.y;
            Bs[kk + 2][r] = bv.z; Bs[kk + 3][r] = bv.w;
        }
        __syncthreads();
        #pragma unroll
        for (int kk = 0; kk < GK; ++kk) {
            const float4 a4 = *(const float4*)&As[kk][ty * 4];
            const float4 b4 = *(const float4*)&Bs[kk][tx * 4];
            const float aa[4] = {a4.x, a4.y, a4.z, a4.w};
            const float bb[4] = {b4.x, b4.y, b4.z, b4.w};
            #pragma unroll
            for (int ii = 0; ii < 4; ++ii)
                #pragma unroll
                for (int jj = 0; jj < 4; ++jj)
                    acc[ii][jj] = fmaf(aa[ii], bb[jj], acc[ii][jj]);
        }
        __syncthreads();
    }
    #pragma unroll
    for (int ii = 0; ii < 4; ++ii) {
        const int t = t0 + ty * 4 + ii;
        if (t < N_FRAMES) {
            #pragma unroll
            for (int jj = 0; jj < 4; ++jj)
                part[(size_t)kb * (N_FRAMES * N_CELLS) + (size_t)t * N_CELLS + c0 + tx * 4 + jj] = acc[ii][jj];
        }
    }
}

// ============== reduce split-K partials ==============
__global__ void reduce_part_k(const float* __restrict__ part, float* __restrict__ spat) {
    int i = blockIdx.x * 256 + threadIdx.x;
    if (i < N_FRAMES * N_CELLS) {
        float s = 0.f;
        #pragma unroll
        for (int kb = 0; kb < KSPLIT; ++kb) s += part[(size_t)kb * (N_FRAMES * N_CELLS) + i];
        spat[i] = s;
    }
}

// ============== stim[t][c] = bias[c] + sum_k fw[t,k]*spat[fs[t,k]][c] ==============
__global__ void stim_k(const float* __restrict__ spat, const float* __restrict__ bias,
                       const float* __restrict__ fw, const int* __restrict__ fs,
                       float* __restrict__ stimb) {
    int i = blockIdx.x * 256 + threadIdx.x;
    if (i < NBT * N_CELLS) {
        const int t = i >> 9, c = i & (N_CELLS - 1);
        const int t2 = t * 2;
        float v = bias[c];
        v = fmaf(fw[t2],     spat[(size_t)fs[t2]     * N_CELLS + c], v);
        v = fmaf(fw[t2 + 1], spat[(size_t)fs[t2 + 1] * N_CELLS + c], v);
        stimb[i] = v;
    }
}

// ============== copy initial spikes into out[c][0..99] ==============
__global__ void copy_init_k(const float* __restrict__ ini, float* __restrict__ out) {
    int i = blockIdx.x * 256 + threadIdx.x;
    if (i < N_CELLS * N_INIT) {
        const int c = i / N_INIT;
        const int j = i - c * N_INIT;
        out[(size_t)c * NBT + j] = ini[i];
    }
}

__device__ __forceinline__ int wrap_slot(int t) {
    int s = t % RING;
    return (s < 0) ? s + RING : s;
}

// ============== persistent scan: lag-register pipeline, sparse-wait exchange ==============
// Exchange word for step s: (uint16)(s+1) << 16 | bf16_bits(spike). 4B, tag exact (s+1 <= 1400).
__global__ __launch_bounds__(SCAN_THREADS) void scan_k(
        const float* __restrict__ stimb,  // [1500][512]
        const float* __restrict__ cf,     // [512][20][100]
        const float* __restrict__ ff,     // [512][100]
        const int*   __restrict__ sel,    // [512][20]
        const float* __restrict__ ini,    // [512][100]
        uint32_t* __restrict__ X32,       // [XDEPTH][512] tagged exchange
        float* __restrict__ out)          // [512][1500]
{
    __shared__ __hip_bfloat16 win[N_CELLS][RSTR];   // spike-history ring, all cells

    const int tid  = threadIdx.x;
    const int wave = tid >> 6;
    const int lane = tid & 63;
    const int cell = blockIdx.x * CPW + wave;

    // ---- poll duty: lane m (m<=20) tracks source m; lags 1..3 held in regs y0,y1,y2 ----
    int psrc = 0;
    float pc1 = 0.f, pc2 = 0.f, pc3 = 0.f;
    float y0 = 0.f, y1 = 0.f, y2 = 0.f;
    if (lane <= MAXC) {
        const int s = (lane < MAXC) ? sel[cell * MAXC + lane] : cell;
        const float* f = (lane < MAXC) ? (cf + (size_t)(cell * MAXC + lane) * NBF)
                                       : (ff + (size_t)cell * NBF);
        psrc = s;
        pc1 = f[99]; pc2 = f[98]; pc3 = f[97];     // lags 1,2,3
        y0 = ini[s * N_INIT + 99];                  // y_{-1}(s)
        y1 = ini[s * N_INIT + 98];                  // y_{-2}(s)
        y2 = ini[s * N_INIT + 97];                  // y_{-3}(s)
    }

    // ---- partial duty: lane l handles lag l+4 (c1v) and lag l+68 (c2v, l<=32) ----
    int   srcm[MAXC + 1];
    float c1v[MAXC + 1], c2v[MAXC + 1];
    #pragma unroll
    for (int m = 0; m <= MAXC; ++m) {
        const int s = (m < MAXC) ? sel[cell * MAXC + m] : cell;
        const float* f = (m < MAXC) ? (cf + (size_t)(cell * MAXC + m) * NBF)
                                    : (ff + (size_t)cell * NBF);
        srcm[m] = s;
        c1v[m]  = f[96 - lane];                        // lag lane+4 -> idx 96..33
        c2v[m]  = (lane <= 32) ? f[32 - lane] : 0.f;   // lag lane+68 -> idx 32..0
    }

    // ---- window init: zero ring, then initial spikes at times -100..-1 ----
    {
        __hip_bfloat16* wf = &win[0][0];
        for (int i = tid; i < N_CELLS * RSTR; i += SCAN_THREADS) wf[i] = __float2bfloat16(0.f);
        __syncthreads();
        for (int i = tid; i < N_CELLS * N_INIT; i += SCAN_THREADS) {
            const int c = i / N_INIT;
            const int b = i - c * N_INIT;
            win[c][wrap_slot(b - N_INIT)] = __float2bfloat16(ini[i]);
        }
    }
    __syncthreads();

    int sp1 = wrap_slot(-4 - lane);     // slot(time P - (lane+4)) for next partial P=0
    int sp2 = wrap_slot(-68 - lane);
    int ws  = 0;                        // slot(j) for ingest j = 0,1,2,...

    float stim_cur = (lane == 0) ? stimb[(size_t)(N_INIT - 1) * N_CELLS + cell] : 0.f;

    // partial(0): lags 4..100 from init window
    float partial;
    {
        float p = 0.f;
        #pragma unroll
        for (int m = 0; m <= MAXC; ++m) {
            p = fmaf(__bfloat162float(win[srcm[m]][sp1]), c1v[m], p);
            p = fmaf(__bfloat162float(win[srcm[m]][sp2]), c2v[m], p);
        }
        #pragma unroll
        for (int off = 32; off > 0; off >>= 1) p += __shfl_xor(p, off, 64);
        partial = p;
    }

    for (int i = 0; i < T_STEPS; ++i) {
        // ---- A: critical path — poll own source's step i-1 word only ----
        if (i > 0) {
            y2 = y1; y1 = y0;
            if (lane <= MAXC) {
                const uint32_t* wp = &X32[(size_t)((i - 1) & (XDEPTH - 1)) * N_CELLS + psrc];
                uint32_t w;
                do {
                    w = __hip_atomic_load(wp, __ATOMIC_RELAXED, __HIP_MEMORY_SCOPE_AGENT);
                } while ((w >> 16) != (uint32_t)i);
                y0 = __uint_as_float((w & 0xffffu) << 16);
            }
        }
        float term = y0 * pc1;
        term = fmaf(y1, pc2, term);
        term = fmaf(y2, pc3, term);
        #pragma unroll
        for (int off = 16; off > 0; off >>= 1) term += __shfl_xor(term, off, 32);

        if (lane == 0) {
            const float g = stim_cur + partial + term;
            const float s = 1.f / (1.f + __expf(-g));
            __hip_bfloat16 hb = __float2bfloat16(s);
            const uint32_t us = (uint32_t)*reinterpret_cast<unsigned short*>(&hb);
            const uint32_t pw = ((uint32_t)(i + 1) << 16) | us;
            __hip_atomic_store(&X32[(size_t)(i & (XDEPTH - 1)) * N_CELLS + cell], pw,
                               __ATOMIC_RELAXED, __HIP_MEMORY_SCOPE_AGENT);
            out[(size_t)cell * NBT + N_INIT + i] = s;
        }

        // ---- B: slack work — ingest full step j=i-3, prefetch stim, partial(i+1) ----
        const int j = i - 3;
        if (j >= 0) {
            const uint32_t* ip = &X32[(size_t)(j & (XDEPTH - 1)) * N_CELLS + tid];
            uint32_t w;
            do {
                w = __hip_atomic_load(ip, __ATOMIC_RELAXED, __HIP_MEMORY_SCOPE_AGENT);
            } while ((w >> 16) != (uint32_t)(j + 1));
            unsigned short us = (unsigned short)(w & 0xffffu);
            win[tid][ws] = *reinterpret_cast<__hip_bfloat16*>(&us);
            ws = (ws + 1 == RING) ? 0 : ws + 1;
        }
        float stim_next = 0.f;
        if (lane == 0) stim_next = stimb[(size_t)(N_INIT + i) * N_CELLS + cell];

        __syncthreads();

        sp1 = (sp1 + 1 == RING) ? 0 : sp1 + 1;
        sp2 = (sp2 + 1 == RING) ? 0 : sp2 + 1;
        float p = 0.f;
        #pragma unroll
        for (int m = 0; m <= MAXC; ++m) {
            p = fmaf(__bfloat162float(win[srcm[m]][sp1]), c1v[m], p);
            p = fmaf(__bfloat162float(win[srcm[m]][sp2]), c2v[m], p);
        }
        #pragma unroll
        for (int off = 32; off > 0; off >>= 1) p += __shfl_xor(p, off, 64);
        partial = p;
        stim_cur = stim_next;
    }
}

extern "C" void kernel_launch(void* const* d_in, const int* in_sizes, int n_in,
                              void* d_out, int out_size, void* d_ws, size_t ws_size,
                              hipStream_t stream) {
    const float* ini    = (const float*)d_in[0];   // initial_spikes [512][100]
    const float* frames = (const float*)d_in[1];   // input_frames  [300][25600]
    const float* sfil   = (const float*)d_in[2];   // spat_filters  [512][25600]
    const float* ff     = (const float*)d_in[3];   // feedback_filters [512][100]
    const float* cf     = (const float*)d_in[4];   // coupling_filters [512][20][100]
    const float* bias   = (const float*)d_in[5];   // [512][1]
    const float* fw     = (const float*)d_in[6];   // forward_weights [1500][2]
    const int*   sel    = (const int*)d_in[7];     // coupled_sel [512][20]
    const int*   fs     = (const int*)d_in[8];     // forward_sel [1500][2]
    float* out = (float*)d_out;
    float* ws  = (float*)d_ws;

    // ws layout (floats):
    //   spat  @ 0       (153600)
    //   stimb @ 153600  (768000)
    //   X32   @ 921600  (XDEPTH*512 u32 = 4096 floats worth of bytes / 4)
    //   part  @ 153600  (KSPLIT*153600, overlaps stimb+X32; dead after reduce)
    float* spat  = ws;
    float* stimb = ws + 153600;
    uint32_t* X32 = (uint32_t*)(ws + 153600 + 768000);
    float* part  = ws + 153600;

    hipLaunchKernelGGL(gemm_partial_k,
                       dim3(KSPLIT, (N_FRAMES + GT - 1) / GT, N_CELLS / GC), dim3(256), 0, stream,
                       frames, sfil, part);
    hipLaunchKernelGGL(reduce_part_k, dim3((N_FRAMES * N_CELLS + 255) / 256), dim3(256), 0, stream, part, spat);
    hipLaunchKernelGGL(stim_k, dim3((NBT * N_CELLS + 255) / 256), dim3(256), 0, stream, spat, bias, fw, fs, stimb);
    hipMemsetAsync(X32, 0, (size_t)XDEPTH * N_CELLS * sizeof(uint32_t), stream);
    hipLaunchKernelGGL(copy_init_k, dim3((N_CELLS * N_INIT + 255) / 256), dim3(256), 0, stream, ini, out);
    hipLaunchKernelGGL(scan_k, dim3(NWG), dim3(SCAN_THREADS), 0, stream,
                       stimb, cf, ff, sel, ini, X32, out);
}